// Round 15
// baseline (54.659 us; speedup 1.0000x reference)
//
#include <hip/hip_runtime.h>
#include <math.h>

#define DIMS 512
#define BATCH 1024
#define CLS 256
#define ROWS (BATCH + CLS)   // 1280 stacked rows: [f_norm; w_norm]
#define NBLK 80              // 80 blocks x 4 waves = 320 waves, all co-resident

#define EPS_PD 1e-6f
#define DEPS2 (512.0f * 1e-6f * 1e-6f)   // D * eps^2
#define EPS_NORM 1e-12f

// fnw swizzled layout (bf16): element (r,k) at
//   (r>>4)*8192 + (k>>3)*128 + (r&15)*8 + (k&7)
// => MFMA fragment load (16 rows x 8 k) = fnw + g*8192 + k0*16 + lane*8:
//    one contiguous 1KB wave transaction. (Verified: absmax 0 in R12/R13.)

typedef short bf16x8 __attribute__((ext_vector_type(8)));
typedef float f32x4 __attribute__((ext_vector_type(4)));

__device__ __forceinline__ float waveReduceSum(float v) {
#pragma unroll
  for (int off = 32; off > 0; off >>= 1)
    v += __shfl_xor(v, off, 64);
  return v;
}

__device__ __forceinline__ unsigned short f2bf(float x) {
  unsigned int u = __float_as_uint(x);
  u += 0x7fffu + ((u >> 16) & 1u);
  return (unsigned short)(u >> 16);
}

#define FRAG(g, k0) (*(const bf16x8*)(fnw + (size_t)(g) * 8192 + (k0) * 16 + (size_t)lane * 8))

__global__ __launch_bounds__(256) void k_fused(
    const float* __restrict__ feat, const float* __restrict__ wt,
    const float* __restrict__ dscale, const int* __restrict__ use_ds,
    unsigned short* __restrict__ fnw, float* __restrict__ Srow,
    float* __restrict__ partial, unsigned* cnt, float* __restrict__ out) {
  const int tid = threadIdx.x;
  const int lane = tid & 63;
  const int w = tid >> 6;
  const int W = blockIdx.x * 4 + w;      // global wave id, 0..319

  // ---- Phase A: normalize rows 4W..4W+3 into swizzled fnw ----
  // Issue all 8 global loads first (latency overlap), then process.
  float4 A[4], C[4];
#pragma unroll
  for (int rr = 0; rr < 4; ++rr) {
    const int r = W * 4 + rr;
    const float4* s4 = (const float4*)((r < BATCH) ? feat + (size_t)r * DIMS
                                                   : wt + (size_t)(r - BATCH) * DIMS);
    A[rr] = s4[lane * 2];        // k = 8l .. 8l+3
    C[rr] = s4[lane * 2 + 1];    // k = 8l+4 .. 8l+7
  }
#pragma unroll
  for (int rr = 0; rr < 4; ++rr) {
    const int r = W * 4 + rr;
    const float4 a = A[rr], c = C[rr];
    float ss = a.x*a.x + a.y*a.y + a.z*a.z + a.w*a.w
             + c.x*c.x + c.y*c.y + c.z*c.z + c.w*c.w;
    float sm = a.x + a.y + a.z + a.w + c.x + c.y + c.z + c.w;
    ss = waveReduceSum(ss);
    sm = waveReduceSum(sm);
    const float rn = 1.f / fmaxf(sqrtf(ss), EPS_NORM);

    ushort4 p0, p1;
    p0.x = f2bf(a.x * rn); p0.y = f2bf(a.y * rn);
    p0.z = f2bf(a.z * rn); p0.w = f2bf(a.w * rn);
    p1.x = f2bf(c.x * rn); p1.y = f2bf(c.y * rn);
    p1.z = f2bf(c.z * rn); p1.w = f2bf(c.w * rn);

    unsigned short* dst = fnw + (size_t)(r >> 4) * 8192 + (size_t)lane * 128 + (r & 15) * 8;
    *(ushort4*)dst = p0;
    *(ushort4*)(dst + 4) = p1;
    if (lane == 0) Srow[r] = sm * rn;
  }

  // ---- Grid barrier 1 (all fnw/Srow visible). Arrive: one RMW per block.
  // Poll: relaxed atomic LOADs (no RMW ping-pong) + s_sleep.
  __threadfence();
  __syncthreads();
  if (tid == 0)
    __hip_atomic_fetch_add(&cnt[0], 1u, __ATOMIC_RELEASE, __HIP_MEMORY_SCOPE_AGENT);
  if (tid == 0) {
    while (__hip_atomic_load(&cnt[0], __ATOMIC_ACQUIRE, __HIP_MEMORY_SCOPE_AGENT) < NBLK)
      __builtin_amdgcn_s_sleep(1);
  }
  __syncthreads();
  __threadfence();

  // ---- Phase B: one 32x32 MFMA tile per wave ----
  // W < 64: protoc tile of the 256x256 w-Gram; W >= 64: main GEMM tile.
  const bool isProtoc = (W < 64);
  const int M = isProtoc ? W : (W - 64);
  const int iTile = isProtoc ? (M >> 3) * 32 : (M >> 3) * 32;   // row tile base
  const int j0 = (M & 7) * 32;
  const int gA = (isProtoc ? (BATCH + iTile) : iTile) >> 4;
  const int gB = (BATCH + j0) >> 4;

  f32x4 acc00 = {0.f,0.f,0.f,0.f}, acc01 = {0.f,0.f,0.f,0.f};
  f32x4 acc10 = {0.f,0.f,0.f,0.f}, acc11 = {0.f,0.f,0.f,0.f};

  // 1-deep register prefetch, fully unrolled (static indices).
  bf16x8 ca0 = FRAG(gA, 0), ca1 = FRAG(gA + 1, 0);
  bf16x8 cb0 = FRAG(gB, 0), cb1 = FRAG(gB + 1, 0);
#pragma unroll
  for (int k0 = 0; k0 < DIMS; k0 += 32) {
    bf16x8 na0, na1, nb0, nb1;
    const int kn = k0 + 32;
    if (kn < DIMS) {
      na0 = FRAG(gA, kn); na1 = FRAG(gA + 1, kn);
      nb0 = FRAG(gB, kn); nb1 = FRAG(gB + 1, kn);
    }
    acc00 = __builtin_amdgcn_mfma_f32_16x16x32_bf16(ca0, cb0, acc00, 0, 0, 0);
    acc01 = __builtin_amdgcn_mfma_f32_16x16x32_bf16(ca0, cb1, acc01, 0, 0, 0);
    acc10 = __builtin_amdgcn_mfma_f32_16x16x32_bf16(ca1, cb0, acc10, 0, 0, 0);
    acc11 = __builtin_amdgcn_mfma_f32_16x16x32_bf16(ca1, cb1, acc11, 0, 0, 0);
    if (kn < DIMS) { ca0 = na0; ca1 = na1; cb0 = nb0; cb1 = nb1; }
  }

  const int crow = ((lane >> 4) & 3) * 4;  // C/D: col = lane&15, row = crow+q
  const int ccol = lane & 15;
  const float swj0 = Srow[BATCH + j0 + ccol];
  const float swj1 = Srow[BATCH + j0 + 16 + ccol];
  const f32x4 accs[4] = {acc00, acc01, acc10, acc11};

  if (isProtoc) {
    float s = 0.f;
#pragma unroll
    for (int hi = 0; hi < 2; ++hi) {
#pragma unroll
      for (int q = 0; q < 4; ++q) {
        const int i = iTile + hi * 16 + crow + q;
        const float swi = Srow[BATCH + i];
#pragma unroll
        for (int hj = 0; hj < 2; ++hj) {
          const int j = j0 + hj * 16 + ccol;
          const float dot = accs[hi * 2 + hj][q];
          const float swj = hj ? swj1 : swj0;
          float dist;
          if (i == j) {
            dist = sqrtf(DEPS2);           // exact self-distance
          } else {
            const float d2 = 2.f - 2.f * dot + 2.f * EPS_PD * (swi - swj) + DEPS2;
            dist = sqrtf(fmaxf(d2, 0.f));
          }
          s += dist;
        }
      }
    }
    s = waveReduceSum(s);
    if (lane == 0) {
      partial[W] = s;
      __threadfence();                     // make partial visible before arrival
      __hip_atomic_fetch_add(&cnt[1], 1u, __ATOMIC_RELEASE, __HIP_MEMORY_SCOPE_AGENT);
    }
    return;                                // protoc waves done (no out tile)
  }

  // Main waves: wait for the 64 protoc arrivals (usually already done —
  // protoc waves had less total work), then read partials.
  while (__hip_atomic_load(&cnt[1], __ATOMIC_ACQUIRE, __HIP_MEMORY_SCOPE_AGENT) < 64u)
    __builtin_amdgcn_s_sleep(1);
  __threadfence();

  const float S = waveReduceSum(partial[lane]);   // 64 deterministic partials
  const float Ssc = 0.1f * S;
  const float sc = (use_ds[0] != 0) ? fabsf(dscale[0]) : 1.0f;

#pragma unroll
  for (int hi = 0; hi < 2; ++hi) {
#pragma unroll
    for (int q = 0; q < 4; ++q) {
      const int i = iTile + hi * 16 + crow + q;
      const float sfi = Srow[i];
#pragma unroll
      for (int hj = 0; hj < 2; ++hj) {
        const int j = j0 + hj * 16 + ccol;
        const float dot = accs[hi * 2 + hj][q];
        const float swj = hj ? swj1 : swj0;
        const float d2 = 2.f - 2.f * dot + 2.f * EPS_PD * (sfi - swj) + DEPS2;
        const float dist = sqrtf(fmaxf(d2, 0.f));
        out[(size_t)i * CLS + j] = (Ssc - dist) * sc;
      }
    }
  }
}

extern "C" void kernel_launch(void* const* d_in, const int* in_sizes, int n_in,
                              void* d_out, int out_size, void* d_ws, size_t ws_size,
                              hipStream_t stream) {
  const float* feat = (const float*)d_in[0];     // [1024,512]
  const float* wt   = (const float*)d_in[1];     // [256,512]
  const float* ds   = (const float*)d_in[2];     // [1]
  const int*   use  = (const int*)d_in[3];       // scalar
  float* out = (float*)d_out;                    // [1024,256] fp32

  // ws layout: fnw (swizzled bf16) 1,310,720 B ; Srow 1280 f ; partial 64 f ; cnt 2 u32
  unsigned short* fnw = (unsigned short*)d_ws;
  float* fbase   = (float*)((char*)d_ws + (size_t)ROWS * DIMS * 2);
  float* Srow    = fbase;
  float* partial = fbase + ROWS;
  unsigned* cnt  = (unsigned*)(partial + 64);

  hipMemsetAsync(cnt, 0, 2 * sizeof(unsigned), stream);  // reset barrier counters
  k_fused<<<NBLK, 256, 0, stream>>>(feat, wt, ds, use, fnw, Srow, partial, cnt, out);
}

// Round 16
// 20.388 us; speedup vs baseline: 2.6809x; 2.6809x over previous
//
#include <hip/hip_runtime.h>
#include <math.h>

#define DIMS 512
#define BATCH 1024
#define CLS 256
#define ROWS (BATCH + CLS)   // 1280 stacked rows: [f_norm; w_norm]

#define EPS_PD 1e-6f
#define DEPS2 (512.0f * 1e-6f * 1e-6f)   // D * eps^2
#define EPS_NORM 1e-12f

typedef short bf16x8 __attribute__((ext_vector_type(8)));   // 8 bf16 = 4 VGPRs
typedef float f32x4 __attribute__((ext_vector_type(4)));

__device__ __forceinline__ float waveReduceSum(float v) {
#pragma unroll
  for (int off = 32; off > 0; off >>= 1)
    v += __shfl_xor(v, off, 64);
  return v;
}

// round-to-nearest-even float -> bf16 (inputs are normal floats; NaN not expected)
__device__ __forceinline__ unsigned short f2bf(float x) {
  unsigned int u = __float_as_uint(x);
  u += 0x7fffu + ((u >> 16) & 1u);
  return (unsigned short)(u >> 16);
}

// K1: grid = 1280, block = 64. Row r<1024 -> feat, else weight row r-1024.
// Normalize row, cast to bf16 into fnw[r][512]; Srow[r] = sum of normalized comps.
__global__ __launch_bounds__(64) void k_norm(
    const float* __restrict__ feat, const float* __restrict__ wt,
    unsigned short* __restrict__ fnw, float* __restrict__ Srow) {
  const int r = blockIdx.x;
  const int lane = threadIdx.x;
  const float* src = (r < BATCH) ? (feat + (size_t)r * DIMS)
                                 : (wt + (size_t)(r - BATCH) * DIMS);
  const float4* s4 = (const float4*)src;

  float4 a = s4[lane];        // d = lane*4 .. +3
  float4 c = s4[lane + 64];   // d = 256 + lane*4 .. +3

  float ss = a.x*a.x + a.y*a.y + a.z*a.z + a.w*a.w
           + c.x*c.x + c.y*c.y + c.z*c.z + c.w*c.w;
  float sm = a.x + a.y + a.z + a.w + c.x + c.y + c.z + c.w;
  ss = waveReduceSum(ss);
  sm = waveReduceSum(sm);
  const float rn = 1.f / fmaxf(sqrtf(ss), EPS_NORM);

  ushort4 pa, pc;
  pa.x = f2bf(a.x * rn); pa.y = f2bf(a.y * rn);
  pa.z = f2bf(a.z * rn); pa.w = f2bf(a.w * rn);
  pc.x = f2bf(c.x * rn); pc.y = f2bf(c.y * rn);
  pc.z = f2bf(c.z * rn); pc.w = f2bf(c.w * rn);

  ushort4* dst = (ushort4*)(fnw + (size_t)r * DIMS);
  dst[lane] = pa;          // d = lane*4
  dst[lane + 64] = pc;     // d = 256 + lane*4

  if (lane == 0) Srow[r] = sm * rn;
}

// K2: bf16 MFMA GEMM. dots[1280x256] = fnw[1280x512] . (w rows of fnw)^T.
// One wave per 32x32 tile; grid (40, 8); no LDS; fragments from global (L2-hot).
__global__ __launch_bounds__(64) void k_gemm(
    const unsigned short* __restrict__ fnw, float* __restrict__ dots) {
  const int lane = threadIdx.x;
  const int r0 = blockIdx.x * 32;          // output rows (stacked)
  const int j0 = blockIdx.y * 32;          // class cols

  const int lm = lane & 15;                // row/col within fragment
  const int lk = (lane >> 4) * 8;          // k sub-block (0,8,16,24)

  // A fragment rows
  const unsigned short* arow0 = fnw + (size_t)(r0 + lm) * DIMS + lk;
  const unsigned short* arow1 = fnw + (size_t)(r0 + 16 + lm) * DIMS + lk;
  // B fragment rows: B[k][col] = W[col][k], W rows start at stacked row 1024
  const unsigned short* brow0 = fnw + (size_t)(BATCH + j0 + lm) * DIMS + lk;
  const unsigned short* brow1 = fnw + (size_t)(BATCH + j0 + 16 + lm) * DIMS + lk;

  f32x4 acc00 = {0.f,0.f,0.f,0.f}, acc01 = {0.f,0.f,0.f,0.f};
  f32x4 acc10 = {0.f,0.f,0.f,0.f}, acc11 = {0.f,0.f,0.f,0.f};

#pragma unroll
  for (int k0 = 0; k0 < DIMS; k0 += 32) {
    const bf16x8 a0 = *(const bf16x8*)(arow0 + k0);
    const bf16x8 a1 = *(const bf16x8*)(arow1 + k0);
    const bf16x8 b0 = *(const bf16x8*)(brow0 + k0);
    const bf16x8 b1 = *(const bf16x8*)(brow1 + k0);
    acc00 = __builtin_amdgcn_mfma_f32_16x16x32_bf16(a0, b0, acc00, 0, 0, 0);
    acc01 = __builtin_amdgcn_mfma_f32_16x16x32_bf16(a0, b1, acc01, 0, 0, 0);
    acc10 = __builtin_amdgcn_mfma_f32_16x16x32_bf16(a1, b0, acc10, 0, 0, 0);
    acc11 = __builtin_amdgcn_mfma_f32_16x16x32_bf16(a1, b1, acc11, 0, 0, 0);
  }

  // C/D layout: col = lane&15, row = (lane>>4)*4 + q  (m89-verified)
  const int crow = (lane >> 4) * 4;
  const int ccol = lane & 15;
#pragma unroll
  for (int q = 0; q < 4; ++q) {
    dots[(size_t)(r0 + crow + q) * CLS + (j0 + ccol)]           = acc00[q];
    dots[(size_t)(r0 + crow + q) * CLS + (j0 + 16 + ccol)]      = acc01[q];
    dots[(size_t)(r0 + 16 + crow + q) * CLS + (j0 + ccol)]      = acc10[q];
    dots[(size_t)(r0 + 16 + crow + q) * CLS + (j0 + 16 + ccol)] = acc11[q];
  }
}

// K3: reduce protoc block (stacked rows 1024..1279) to 64 deterministic partials.
// grid = 64, block = 256; each thread one float4 of dots.
__global__ __launch_bounds__(256) void k_red(
    const float* __restrict__ dots, const float* __restrict__ Srow,
    float* __restrict__ partial) {
  const int b = blockIdx.x;
  const int t = threadIdx.x;
  const int g = b * 1024 + t * 4;          // element index within 256x256 block
  const int i = g >> 8;                    // protoc row
  const int j = g & 255;                   // protoc col (j%4==0)

  const float4 d4 = *(const float4*)(dots + (size_t)BATCH * CLS + g);
  const float swi = Srow[BATCH + i];
  const float4 swj = *(const float4*)(Srow + BATCH + j);

  float s = 0.f;
  const float dot[4] = {d4.x, d4.y, d4.z, d4.w};
  const float sw[4] = {swj.x, swj.y, swj.z, swj.w};
#pragma unroll
  for (int e = 0; e < 4; ++e) {
    float dist;
    if (i == j + e) {
      dist = sqrtf(DEPS2);                 // exact diagonal (self-distance)
    } else {
      const float d2 = 2.f - 2.f * dot[e] + 2.f * EPS_PD * (swi - sw[e]) + DEPS2;
      dist = sqrtf(fmaxf(d2, 0.f));
    }
    s += dist;
  }

  __shared__ float red[4];
  float ws = waveReduceSum(s);
  if ((t & 63) == 0) red[t >> 6] = ws;
  __syncthreads();
  if (t == 0) partial[b] = red[0] + red[1] + red[2] + red[3];
}

// K4: epilogue over the 1024x256 main block. grid = 256, block = 256, float4 each.
__global__ __launch_bounds__(256) void k_epi(
    const float* __restrict__ dots, const float* __restrict__ Srow,
    const float* __restrict__ partial, const float* __restrict__ dscale,
    const int* __restrict__ use_ds, float* __restrict__ out) {
  const int t = threadIdx.x;

  __shared__ float sS;
  if (t < 64) {
    float v = partial[t];
    v = waveReduceSum(v);
    if (t == 0) sS = v;
  }
  __syncthreads();
  const float Ssc = 0.1f * sS;
  const float sc = (use_ds[0] != 0) ? fabsf(dscale[0]) : 1.0f;

  const int g = (blockIdx.x * 256 + t) * 4;  // element index within 1024x256
  const int i = g >> 8;                      // feature row
  const int j = g & 255;                     // class col (j%4==0)

  const float4 d4 = *(const float4*)(dots + g);
  const float sfi = Srow[i];
  const float4 swj = *(const float4*)(Srow + BATCH + j);

  const float dot[4] = {d4.x, d4.y, d4.z, d4.w};
  const float sw[4] = {swj.x, swj.y, swj.z, swj.w};
  float4 o;
  float* op = (float*)&o;
#pragma unroll
  for (int e = 0; e < 4; ++e) {
    const float d2 = 2.f - 2.f * dot[e] + 2.f * EPS_PD * (sfi - sw[e]) + DEPS2;
    const float dist = sqrtf(fmaxf(d2, 0.f));
    op[e] = (Ssc - dist) * sc;
  }
  *(float4*)(out + g) = o;
}

extern "C" void kernel_launch(void* const* d_in, const int* in_sizes, int n_in,
                              void* d_out, int out_size, void* d_ws, size_t ws_size,
                              hipStream_t stream) {
  const float* feat = (const float*)d_in[0];     // [1024,512]
  const float* wt   = (const float*)d_in[1];     // [256,512]
  const float* ds   = (const float*)d_in[2];     // [1]
  const int*   use  = (const int*)d_in[3];       // scalar
  float* out = (float*)d_out;                    // [1024,256] fp32

  // ws layout (bytes): fnw bf16 1280*512*2 = 1,310,720 ; then floats
  unsigned short* fnw = (unsigned short*)d_ws;
  float* fbase   = (float*)((char*)d_ws + (size_t)ROWS * DIMS * 2);
  float* Srow    = fbase;                        // 1280
  float* partial = fbase + ROWS;                 // 64
  float* dots    = fbase + ROWS + 64;            // 1280*256 (16B-aligned: offset 1344 floats)

  k_norm<<<ROWS, 64, 0, stream>>>(feat, wt, fnw, Srow);
  k_gemm<<<dim3(ROWS / 32, CLS / 32), 64, 0, stream>>>(fnw, dots);
  k_red<<<64, 256, 0, stream>>>(dots, Srow, partial);
  k_epi<<<256, 256, 0, stream>>>(dots, Srow, partial, ds, use, out);
}